// Round 2
// baseline (4375.962 us; speedup 1.0000x reference)
//
#include <hip/hip_runtime.h>
#include <hip/hip_bf16.h>
#include <math.h>

// DeepseekV32 MLA attention + lightning indexer, MI355X (gfx950).
// Round 2: same all-f32 pipeline as R1, but d_out is FLOAT32 (reference
// output dtype is f32; R1's bf16 write was the failure). ~128.2 MB ws.

namespace {

constexpr int T_    = 2048;
constexpr int HID_  = 7168;
constexpr int H_    = 16;
constexpr int QLR_  = 1536;
constexpr int KVLR_ = 512;
constexpr int IH_   = 32;
constexpr int ID_   = 128;
constexpr int TOPK_ = 512;
constexpr float EPS_    = 1e-6f;
constexpr float SCALE_  = 0.07216878364870322f;   // (128+64)^-0.5
constexpr float ISCALE_ = 0.08838834764831845f;   // 128^-0.5
constexpr float WSCALE_ = 0.17677669529663687f;   // 32^-0.5

__device__ __forceinline__ unsigned int mono(float x) {
  // order-preserving float->uint transform
  unsigned int u = __float_as_uint(x);
  return (u & 0x80000000u) ? ~u : (u | 0x80000000u);
}

// ---------------- rope tables: cos/sin (T,32) ----------------
__global__ void k_tables(const int* __restrict__ pos, float* __restrict__ cosT,
                         float* __restrict__ sinT) {
  int idx = blockIdx.x * 256 + threadIdx.x;
  if (idx >= T_ * 32) return;
  int t = idx >> 5, i = idx & 31;
  float invf = (float)pow(10000.0, -(double)i / 32.0);
  float ang = (float)pos[t] * invf;
  cosT[idx] = cosf(ang);
  sinT[idx] = sinf(ang);
}

// ---------------- rmsnorm (block per row) ----------------
template <int N>
__launch_bounds__(256)
__global__ void k_rms(const float* __restrict__ x, const float* __restrict__ w,
                      float* __restrict__ y) {
  int t = blockIdx.x;
  const float* xr = x + (size_t)t * N;
  float ss = 0.f;
  for (int c = threadIdx.x; c < N; c += 256) { float v = xr[c]; ss += v * v; }
  __shared__ float red[256];
  red[threadIdx.x] = ss;
  __syncthreads();
  for (int off = 128; off > 0; off >>= 1) {
    if (threadIdx.x < off) red[threadIdx.x] += red[threadIdx.x + off];
    __syncthreads();
  }
  float sc = rsqrtf(red[0] * (1.f / N) + EPS_);
  float* yr = y + (size_t)t * N;
  for (int c = threadIdx.x; c < N; c += 256) yr[c] = xr[c] * sc * w[c];
}

// ---------------- generic f32 GEMM: C(M,N) = A(M,K) @ B(K,N) ----------------
__launch_bounds__(256)
__global__ void k_gemm(const float* __restrict__ A, const float* __restrict__ B,
                       float* __restrict__ C, int M, int N, int K) {
  __shared__ float As[16][68];  // transposed: As[k][i]
  __shared__ float Bs[16][68];  // Bs[k][j]
  int m0 = blockIdx.y * 64, n0 = blockIdx.x * 64;
  int tid = threadIdx.x;
  int ti = tid & 15, tj = tid >> 4;
  int ar = tid >> 2, akq = tid & 3;
  int bkr = tid >> 4, bjq = tid & 15;
  float acc[4][4] = {};
  for (int k0 = 0; k0 < K; k0 += 16) {
    float4 a4 = *(const float4*)&A[(size_t)(m0 + ar) * K + k0 + akq * 4];
    float4 b4 = *(const float4*)&B[(size_t)(k0 + bkr) * N + n0 + bjq * 4];
    As[akq * 4 + 0][ar] = a4.x;
    As[akq * 4 + 1][ar] = a4.y;
    As[akq * 4 + 2][ar] = a4.z;
    As[akq * 4 + 3][ar] = a4.w;
    *(float4*)&Bs[bkr][bjq * 4] = b4;
    __syncthreads();
#pragma unroll
    for (int k = 0; k < 16; ++k) {
      float4 av = *(const float4*)&As[k][ti * 4];
      float4 bv = *(const float4*)&Bs[k][tj * 4];
      float ax[4] = {av.x, av.y, av.z, av.w};
      float bx[4] = {bv.x, bv.y, bv.z, bv.w};
#pragma unroll
      for (int r = 0; r < 4; ++r)
#pragma unroll
        for (int c = 0; c < 4; ++c) acc[r][c] = fmaf(ax[r], bx[c], acc[r][c]);
    }
    __syncthreads();
  }
#pragma unroll
  for (int r = 0; r < 4; ++r) {
    float4 st = make_float4(acc[r][0], acc[r][1], acc[r][2], acc[r][3]);
    *(float4*)&C[(size_t)(m0 + ti * 4 + r) * N + n0 + tj * 4] = st;
  }
}

// ---------------- rope on q_pe (interleaved, in-place on q buffer) ----------------
__global__ void k_rope_q(float* __restrict__ q, const float* __restrict__ cosT,
                         const float* __restrict__ sinT) {
  int idx = blockIdx.x * 256 + threadIdx.x;
  if (idx >= T_ * H_ * 32) return;
  int i = idx & 31;
  int th = idx >> 5;
  int h = th & 15, t = th >> 4;
  float c = cosT[t * 32 + i], s = sinT[t * 32 + i];
  float* p = q + (size_t)t * 3072 + h * 192 + 128 + 2 * i;
  float e = p[0], o = p[1];
  p[0] = e * c - o * s;
  p[1] = o * c + e * s;
}

// ---------------- rope neox on q_idx first 64 dims (in-place) ----------------
__global__ void k_rope_qidx(float* __restrict__ qi, const float* __restrict__ cosT,
                            const float* __restrict__ sinT) {
  int idx = blockIdx.x * 256 + threadIdx.x;
  if (idx >= T_ * IH_ * 32) return;
  int i = idx & 31;
  int th = idx >> 5;
  int h = th & 31, t = th >> 5;
  float c = cosT[t * 32 + i], s = sinT[t * 32 + i];
  float* p = qi + (size_t)t * 4096 + h * 128;
  float a = p[i], b = p[i + 32];
  p[i] = a * c - b * s;
  p[i + 32] = b * c + a * s;
}

// ---------------- rope interleaved on k_pe -> k_pe_r ----------------
__global__ void k_rope_kpe(const float* __restrict__ kpe, const float* __restrict__ cosT,
                           const float* __restrict__ sinT, float* __restrict__ kper) {
  int idx = blockIdx.x * 256 + threadIdx.x;
  if (idx >= T_ * 32) return;
  int i = idx & 31, t = idx >> 5;
  float c = cosT[idx], s = sinT[idx];
  float e = kpe[(size_t)t * 64 + 2 * i], o = kpe[(size_t)t * 64 + 2 * i + 1];
  kper[(size_t)t * 64 + 2 * i] = e * c - o * s;
  kper[(size_t)t * 64 + 2 * i + 1] = o * c + e * s;
}

// ---------------- k_idx: (hidden @ Wik) -> layernorm -> rope neox ----------------
__launch_bounds__(256)
__global__ void k_kidx(const float* __restrict__ hidden, const float* __restrict__ Wik,
                       const float* __restrict__ gamma, const float* __restrict__ beta,
                       const float* __restrict__ cosT, const float* __restrict__ sinT,
                       float* __restrict__ kidx) {
  int t = blockIdx.x;
  int c = threadIdx.x & 127;
  int s = threadIdx.x >> 7;  // 0..1 k-slices
  const float* hr = hidden + (size_t)t * HID_;
  float acc = 0.f;
  int k0 = s * (HID_ / 2), k1 = k0 + (HID_ / 2);
  for (int k = k0; k < k1; ++k) acc = fmaf(hr[k], Wik[(size_t)k * ID_ + c], acc);
  __shared__ float part[2][ID_];
  __shared__ float red[128];
  __shared__ float sm[2];
  __shared__ float yn[ID_];
  part[s][c] = acc;
  __syncthreads();
  float yv = 0.f;
  if (s == 0) { yv = part[0][c] + part[1][c]; red[c] = yv; }
  __syncthreads();
  for (int off = 64; off > 0; off >>= 1) {
    if (threadIdx.x < off) red[threadIdx.x] += red[threadIdx.x + off];
    __syncthreads();
  }
  if (threadIdx.x == 0) sm[0] = red[0] * (1.f / ID_);
  __syncthreads();
  float mu = sm[0];
  if (s == 0) { float d = yv - mu; red[c] = d * d; }
  __syncthreads();
  for (int off = 64; off > 0; off >>= 1) {
    if (threadIdx.x < off) red[threadIdx.x] += red[threadIdx.x + off];
    __syncthreads();
  }
  if (threadIdx.x == 0) sm[1] = red[0] * (1.f / ID_);
  __syncthreads();
  if (s == 0) {
    float rstd = rsqrtf(sm[1] + EPS_);
    yn[c] = (yv - mu) * rstd * gamma[c] + beta[c];
  }
  __syncthreads();
  if (threadIdx.x < 32) {
    int i = threadIdx.x;
    float co = cosT[t * 32 + i], si = sinT[t * 32 + i];
    float a = yn[i], b = yn[i + 32];
    kidx[(size_t)t * ID_ + i] = a * co - b * si;
    kidx[(size_t)t * ID_ + i + 32] = b * co + a * si;
  } else if (threadIdx.x >= 64 && threadIdx.x < 128) {
    kidx[(size_t)t * ID_ + threadIdx.x] = yn[threadIdx.x];
  }
}

// ---------------- w_idx = hidden @ Ww * 32^-0.5 ----------------
__launch_bounds__(256)
__global__ void k_widx(const float* __restrict__ hidden, const float* __restrict__ Ww,
                       float* __restrict__ widx) {
  int t = blockIdx.x;
  int j = threadIdx.x & 31, s = threadIdx.x >> 5;  // 8 slices of 896
  const float* hr = hidden + (size_t)t * HID_;
  float acc = 0.f;
  int k0 = s * 896, k1 = k0 + 896;
  for (int k = k0; k < k1; ++k) acc = fmaf(hr[k], Ww[(size_t)k * 32 + j], acc);
  __shared__ float red[8][33];
  red[s][j] = acc;
  __syncthreads();
  if (threadIdx.x < 32) {
    float v = 0.f;
#pragma unroll
    for (int r = 0; r < 8; ++r) v += red[r][j];
    widx[(size_t)t * 32 + j] = v * WSCALE_;
  }
}

// ---------------- indexer scores ----------------
__launch_bounds__(256)
__global__ void k_scores(const float* __restrict__ qidx, const float* __restrict__ kidx,
                         const float* __restrict__ widx, float* __restrict__ scores) {
  int jb = blockIdx.x, tb = blockIdx.y;
  int t0 = tb * 32, j0 = jb * 64;
  if (j0 > t0 + 31) return;  // fully non-causal tile
  int tid = threadIdx.x;
  __shared__ float KsT[128][68];  // [d][j]
  __shared__ float QsT[128][36];  // [d][i]
  __shared__ float Wsh[32][33];   // [i][h]
  for (int m = 0; m < 32; ++m) {
    int e = m * 256 + tid;
    int j = e >> 7, d = e & 127;
    KsT[d][j] = kidx[(size_t)(j0 + j) * 128 + d];
  }
  for (int m = 0; m < 4; ++m) {
    int e = m * 256 + tid;
    int i = e >> 5, hh = e & 31;
    Wsh[i][hh] = widx[(size_t)(t0 + i) * 32 + hh];
  }
  int ti = tid & 15, tj = tid >> 4;
  float sacc[2][4] = {};
  for (int h = 0; h < 32; ++h) {
    __syncthreads();  // protect QsT (and cover KsT/Wsh staging at h==0)
    for (int m = 0; m < 16; ++m) {
      int e = m * 256 + tid;
      int i = e >> 7, d = e & 127;
      QsT[d][i] = qidx[(size_t)(t0 + i) * 4096 + h * 128 + d];
    }
    __syncthreads();
    float lacc[2][4] = {};
    for (int d = 0; d < 128; ++d) {
      float2 a = *(const float2*)&QsT[d][ti * 2];
      float4 b = *(const float4*)&KsT[d][tj * 4];
      lacc[0][0] = fmaf(a.x, b.x, lacc[0][0]);
      lacc[0][1] = fmaf(a.x, b.y, lacc[0][1]);
      lacc[0][2] = fmaf(a.x, b.z, lacc[0][2]);
      lacc[0][3] = fmaf(a.x, b.w, lacc[0][3]);
      lacc[1][0] = fmaf(a.y, b.x, lacc[1][0]);
      lacc[1][1] = fmaf(a.y, b.y, lacc[1][1]);
      lacc[1][2] = fmaf(a.y, b.z, lacc[1][2]);
      lacc[1][3] = fmaf(a.y, b.w, lacc[1][3]);
    }
#pragma unroll
    for (int r = 0; r < 2; ++r) {
      float wv = Wsh[ti * 2 + r][h];
#pragma unroll
      for (int c = 0; c < 4; ++c)
        sacc[r][c] = fmaf(wv, fmaxf(lacc[r][c] * ISCALE_, 0.f), sacc[r][c]);
    }
  }
#pragma unroll
  for (int r = 0; r < 2; ++r) {
    float4 st = make_float4(sacc[r][0], sacc[r][1], sacc[r][2], sacc[r][3]);
    *(float4*)&scores[(size_t)(t0 + ti * 2 + r) * T_ + j0 + tj * 4] = st;
  }
}

// ---------------- top-k threshold ----------------
__launch_bounds__(256)
__global__ void k_topk(const float* __restrict__ scores, unsigned int* __restrict__ kth) {
  int t = blockIdx.x;
  int n = t + 1;
  if (n <= TOPK_) {
    if (threadIdx.x == 0) kth[t] = 0u;  // all causal positions allowed
    return;
  }
  unsigned int keys[8];
#pragma unroll
  for (int m = 0; m < 8; ++m) {
    int j = threadIdx.x + m * 256;
    keys[m] = (j < n) ? mono(scores[(size_t)t * T_ + j]) : 0u;
  }
  __shared__ int wred[4];
  unsigned int thr = 0u;
  for (int b = 31; b >= 0; --b) {
    unsigned int cand = thr | (1u << b);
    int c = 0;
#pragma unroll
    for (int m = 0; m < 8; ++m) c += (keys[m] >= cand) ? 1 : 0;
    for (int o = 32; o > 0; o >>= 1) c += __shfl_down(c, o, 64);
    if ((threadIdx.x & 63) == 0) wred[threadIdx.x >> 6] = c;
    __syncthreads();
    int total = wred[0] + wred[1] + wred[2] + wred[3];
    if (total >= TOPK_) thr = cand;
    __syncthreads();
  }
  if (threadIdx.x == 0) kth[t] = thr;
}

// ---------------- flash attention with top-k mask ----------------
__launch_bounds__(256)
__global__ void k_flash(const float* __restrict__ q, const float* __restrict__ kv,
                        const float* __restrict__ kper, const float* __restrict__ scores,
                        const unsigned int* __restrict__ kth, float* __restrict__ obuf) {
  int tb = blockIdx.x, h = blockIdx.y;
  int t0 = tb * 16;
  int tid = threadIdx.x;
  __shared__ float QT[192][18];   // [d][i]
  __shared__ float KT[192][34];   // [d][j]
  __shared__ float Vs[32][132];   // [j][d]
  __shared__ float Ps[16][33];    // [i][j]
  __shared__ float Mred[16][17];  // [tj][i]
  __shared__ float m_s[16], l_s[16], alpha_s[16], mnew_s[16];

  {
    int i = tid >> 4, l16 = tid & 15;
    const float* qr = q + (size_t)(t0 + i) * 3072 + h * 192;
#pragma unroll
    for (int m = 0; m < 12; ++m) { int d = m * 16 + l16; QT[d][i] = qr[d]; }
  }
  if (tid < 16) { m_s[tid] = -INFINITY; l_s[tid] = 0.f; }

  float O[8];
#pragma unroll
  for (int dd = 0; dd < 8; ++dd) O[dd] = 0.f;

  int ti = tid & 15, tj = tid >> 4;
  int io = tid >> 4, db = tid & 15;

  int jt_max = (t0 + 15) >> 5;
  for (int jt = 0; jt <= jt_max; ++jt) {
    int j0 = jt * 32;
    __syncthreads();
    for (int m = 0; m < 16; ++m) {
      int e = m * 256 + tid;
      int j = e >> 7, d = e & 127;
      const float* kvr = kv + (size_t)(j0 + j) * 4096 + h * 256;
      KT[d][j] = kvr[d];
      Vs[j][d] = kvr[128 + d];
    }
    for (int m = 0; m < 8; ++m) {
      int e = m * 256 + tid;
      int j = e >> 6, r = e & 63;
      KT[128 + r][j] = kper[(size_t)(j0 + j) * 64 + r];
    }
    __syncthreads();

    float S0 = 0.f, S1 = 0.f;
#pragma unroll 16
    for (int d = 0; d < 192; ++d) {
      float qv = QT[d][ti];
      float2 kf = *(const float2*)&KT[d][tj * 2];
      S0 = fmaf(qv, kf.x, S0);
      S1 = fmaf(qv, kf.y, S1);
    }
    int ig = t0 + ti;
    {
      unsigned int kt = kth[ig];
      int jg = j0 + tj * 2;
      bool ok0 = (jg <= ig) && (mono(scores[(size_t)ig * T_ + jg]) >= kt);
      bool ok1 = (jg + 1 <= ig) && (mono(scores[(size_t)ig * T_ + jg + 1]) >= kt);
      S0 = ok0 ? S0 * SCALE_ : -INFINITY;
      S1 = ok1 ? S1 * SCALE_ : -INFINITY;
    }
    Mred[tj][ti] = fmaxf(S0, S1);
    __syncthreads();
    if (tid < 16) {
      float mt = -INFINITY;
#pragma unroll
      for (int w = 0; w < 16; ++w) mt = fmaxf(mt, Mred[w][tid]);
      float mo = m_s[tid];
      float mn = fmaxf(mo, mt);
      mnew_s[tid] = mn;
      alpha_s[tid] = (mo == -INFINITY) ? 0.f : expf(mo - mn);
      m_s[tid] = mn;
    }
    __syncthreads();
    float mn = mnew_s[ti];
    float p0 = (S0 == -INFINITY) ? 0.f : expf(S0 - mn);
    float p1 = (S1 == -INFINITY) ? 0.f : expf(S1 - mn);
    Ps[ti][tj * 2 + 0] = p0;
    Ps[ti][tj * 2 + 1] = p1;
    Mred[tj][ti] = p0 + p1;
    __syncthreads();
    if (tid < 16) {
      float st = 0.f;
#pragma unroll
      for (int w = 0; w < 16; ++w) st += Mred[w][tid];
      l_s[tid] = alpha_s[tid] * l_s[tid] + st;
    }
    float al = alpha_s[io];
#pragma unroll
    for (int dd = 0; dd < 8; ++dd) O[dd] *= al;
    for (int j = 0; j < 32; ++j) {
      float p = Ps[io][j];
#pragma unroll
      for (int dd = 0; dd < 8; ++dd) O[dd] = fmaf(p, Vs[j][db + dd * 16], O[dd]);
    }
  }
  __syncthreads();
  float inv = 1.f / l_s[io];
  float* orow = obuf + (size_t)(t0 + io) * 2048 + h * 128;
#pragma unroll
  for (int dd = 0; dd < 8; ++dd) orow[db + dd * 16] = O[dd] * inv;
}

}  // namespace

extern "C" void kernel_launch(void* const* d_in, const int* in_sizes, int n_in,
                              void* d_out, int out_size, void* d_ws, size_t ws_size,
                              hipStream_t stream) {
  (void)in_sizes; (void)n_in; (void)out_size; (void)ws_size;
  const int*   positions = (const int*)d_in[0];
  const float* hidden  = (const float*)d_in[1];
  const float* q_c     = (const float*)d_in[2];
  const float* kv_c    = (const float*)d_in[3];
  const float* k_pe    = (const float*)d_in[4];
  const float* q_ln    = (const float*)d_in[5];
  const float* kv_ln   = (const float*)d_in[6];
  const float* Wq_b    = (const float*)d_in[7];
  const float* Wkv_b   = (const float*)d_in[8];
  const float* Wo      = (const float*)d_in[9];
  const float* Wiq     = (const float*)d_in[10];
  const float* Wik     = (const float*)d_in[11];
  const float* ik_g    = (const float*)d_in[12];
  const float* ik_b    = (const float*)d_in[13];
  const float* Ww      = (const float*)d_in[14];
  float* out = (float*)d_out;  // reference output dtype is float32

  float* ws = (float*)d_ws;
  size_t off = 0;
  float* cosT = ws + off; off += (size_t)T_ * 32;
  float* sinT = ws + off; off += (size_t)T_ * 32;
  float* qcn  = ws + off; off += (size_t)T_ * QLR_;
  float* kvn  = ws + off; off += (size_t)T_ * KVLR_;
  float* qbuf = ws + off; off += (size_t)T_ * H_ * 192;   // q (nope+roped pe)
  float* kvb  = ws + off; off += (size_t)T_ * H_ * 256;   // kv (k_nope | v)
  float* qidx = ws + off; off += (size_t)T_ * IH_ * ID_;  // reused as o_buf
  float* kidx = ws + off; off += (size_t)T_ * ID_;
  float* widx = ws + off; off += (size_t)T_ * IH_;
  float* kper = ws + off; off += (size_t)T_ * 64;
  float* scores = ws + off; off += (size_t)T_ * T_;
  unsigned int* kth = (unsigned int*)(ws + off); off += T_;
  float* obuf = qidx;  // qidx dead after k_scores

  k_tables<<<dim3(T_ * 32 / 256), dim3(256), 0, stream>>>(positions, cosT, sinT);
  k_rms<QLR_><<<dim3(T_), dim3(256), 0, stream>>>(q_c, q_ln, qcn);
  k_rms<KVLR_><<<dim3(T_), dim3(256), 0, stream>>>(kv_c, kv_ln, kvn);
  k_gemm<<<dim3(3072 / 64, T_ / 64), dim3(256), 0, stream>>>(qcn, Wq_b, qbuf, T_, 3072, QLR_);
  k_rope_q<<<dim3(T_ * H_ * 32 / 256), dim3(256), 0, stream>>>(qbuf, cosT, sinT);
  k_gemm<<<dim3(4096 / 64, T_ / 64), dim3(256), 0, stream>>>(kvn, Wkv_b, kvb, T_, 4096, KVLR_);
  k_gemm<<<dim3(4096 / 64, T_ / 64), dim3(256), 0, stream>>>(qcn, Wiq, qidx, T_, 4096, QLR_);
  k_rope_qidx<<<dim3(T_ * IH_ * 32 / 256), dim3(256), 0, stream>>>(qidx, cosT, sinT);
  k_kidx<<<dim3(T_), dim3(256), 0, stream>>>(hidden, Wik, ik_g, ik_b, cosT, sinT, kidx);
  k_widx<<<dim3(T_), dim3(256), 0, stream>>>(hidden, Ww, widx);
  k_rope_kpe<<<dim3(T_ * 32 / 256), dim3(256), 0, stream>>>(k_pe, cosT, sinT, kper);
  k_scores<<<dim3(T_ / 64, T_ / 32), dim3(256), 0, stream>>>(qidx, kidx, widx, scores);
  k_topk<<<dim3(T_), dim3(256), 0, stream>>>(scores, kth);
  k_flash<<<dim3(T_ / 16, H_), dim3(256), 0, stream>>>(qbuf, kvb, kper, scores, kth, obuf);
  k_gemm<<<dim3(HID_ / 64, T_ / 64), dim3(256), 0, stream>>>(obuf, Wo, out, T_, HID_, 2048);
}

// Round 3
// 2133.106 us; speedup vs baseline: 2.0515x; 2.0515x over previous
//
#include <hip/hip_runtime.h>
#include <hip/hip_bf16.h>
#include <math.h>

// DeepseekV32 MLA attention + lightning indexer, MI355X (gfx950).
// Round 3: bf16 MFMA for flash attention + Wq_b/Wkv_b/Wo GEMMs.
// Indexer path (Wiq, kidx, scores, topk) stays f32 for selection stability.

namespace {

constexpr int T_    = 2048;
constexpr int HID_  = 7168;
constexpr int H_    = 16;
constexpr int QLR_  = 1536;
constexpr int KVLR_ = 512;
constexpr int IH_   = 32;
constexpr int ID_   = 128;
constexpr int TOPK_ = 512;
constexpr float EPS_    = 1e-6f;
constexpr float SCALE_  = 0.07216878364870322f;   // (128+64)^-0.5
constexpr float ISCALE_ = 0.08838834764831845f;   // 128^-0.5
constexpr float WSCALE_ = 0.17677669529663687f;   // 32^-0.5

typedef __attribute__((ext_vector_type(8))) short bf16x8;
typedef __attribute__((ext_vector_type(4))) float f32x4;

__device__ __forceinline__ unsigned int mono(float x) {
  unsigned int u = __float_as_uint(x);
  return (u & 0x80000000u) ? ~u : (u | 0x80000000u);
}

__device__ __forceinline__ unsigned short f2bf(float x) {
  unsigned int u = __float_as_uint(x);
  u += 0x7FFFu + ((u >> 16) & 1u);
  return (unsigned short)(u >> 16);
}

// ---------------- rope tables ----------------
__global__ void k_tables(const int* __restrict__ pos, float* __restrict__ cosT,
                         float* __restrict__ sinT) {
  int idx = blockIdx.x * 256 + threadIdx.x;
  if (idx >= T_ * 32) return;
  int t = idx >> 5, i = idx & 31;
  float invf = (float)pow(10000.0, -(double)i / 32.0);
  float ang = (float)pos[t] * invf;
  cosT[idx] = cosf(ang);
  sinT[idx] = sinf(ang);
}

// ---------------- rmsnorm: f32 out + bf16 out ----------------
template <int N>
__launch_bounds__(256)
__global__ void k_rms(const float* __restrict__ x, const float* __restrict__ w,
                      float* __restrict__ y, unsigned short* __restrict__ yb) {
  int t = blockIdx.x;
  const float* xr = x + (size_t)t * N;
  float ss = 0.f;
  for (int c = threadIdx.x; c < N; c += 256) { float v = xr[c]; ss += v * v; }
  __shared__ float red[256];
  red[threadIdx.x] = ss;
  __syncthreads();
  for (int off = 128; off > 0; off >>= 1) {
    if (threadIdx.x < off) red[threadIdx.x] += red[threadIdx.x + off];
    __syncthreads();
  }
  float sc = rsqrtf(red[0] * (1.f / N) + EPS_);
  float* yr = y + (size_t)t * N;
  unsigned short* ybr = yb + (size_t)t * N;
  for (int c = threadIdx.x; c < N; c += 256) {
    float v = xr[c] * sc * w[c];
    yr[c] = v;
    ybr[c] = f2bf(v);
  }
}

// ---------------- transpose-cast: W (K x N, f32) -> Wt (N x K, bf16) ----------------
__launch_bounds__(256)
__global__ void k_tc(const float* __restrict__ W, unsigned short* __restrict__ Wt,
                     int K, int N) {
  __shared__ float tile[64][65];
  int k0 = blockIdx.y * 64, n0 = blockIdx.x * 64;
  int tid = threadIdx.x;
#pragma unroll
  for (int i = 0; i < 16; ++i) {
    int e = i * 256 + tid;
    int r = e >> 6, c = e & 63;
    tile[r][c] = W[(size_t)(k0 + r) * N + n0 + c];
  }
  __syncthreads();
#pragma unroll
  for (int i = 0; i < 16; ++i) {
    int e = i * 256 + tid;
    int r = e >> 6, c = e & 63;
    Wt[(size_t)(n0 + r) * K + k0 + c] = f2bf(tile[c][r]);
  }
}

// ---------------- bf16 MFMA GEMM: C(M,N) f32 = A(M,K) bf16 @ Bt(N,K) bf16 ----------------
__launch_bounds__(256)
__global__ void k_gemm_bf(const unsigned short* __restrict__ A,
                          const unsigned short* __restrict__ Bt,
                          float* __restrict__ C, int M, int N, int K) {
  __shared__ unsigned short As[128][40];
  __shared__ unsigned short Bs[128][40];
  int m0 = blockIdx.y * 128, n0 = blockIdx.x * 128;
  int tid = threadIdx.x;
  int w = tid >> 6, lane = tid & 63;
  int quad = lane >> 4, l16 = lane & 15;
  int wr = w & 1, wc = w >> 1;
  f32x4 acc[4][4] = {};
  for (int k0 = 0; k0 < K; k0 += 32) {
    __syncthreads();
#pragma unroll
    for (int i = 0; i < 2; ++i) {
      int c = i * 256 + tid;
      int row = c >> 2, off = (c & 3) * 8;
      *(uint4*)&As[row][off] = *(const uint4*)&A[(size_t)(m0 + row) * K + k0 + off];
      *(uint4*)&Bs[row][off] = *(const uint4*)&Bt[(size_t)(n0 + row) * K + k0 + off];
    }
    __syncthreads();
    bf16x8 a[4], b[4];
#pragma unroll
    for (int mi = 0; mi < 4; ++mi) a[mi] = *(const bf16x8*)&As[64 * wr + 16 * mi + l16][quad * 8];
#pragma unroll
    for (int ni = 0; ni < 4; ++ni) b[ni] = *(const bf16x8*)&Bs[64 * wc + 16 * ni + l16][quad * 8];
#pragma unroll
    for (int mi = 0; mi < 4; ++mi)
#pragma unroll
      for (int ni = 0; ni < 4; ++ni)
        acc[mi][ni] = __builtin_amdgcn_mfma_f32_16x16x32_bf16(a[mi], b[ni], acc[mi][ni], 0, 0, 0);
  }
#pragma unroll
  for (int mi = 0; mi < 4; ++mi)
#pragma unroll
    for (int ni = 0; ni < 4; ++ni)
#pragma unroll
      for (int r = 0; r < 4; ++r) {
        int row = m0 + 64 * wr + 16 * mi + quad * 4 + r;
        int col = n0 + 64 * wc + 16 * ni + l16;
        C[(size_t)row * N + col] = acc[mi][ni][r];
      }
}

// ---------------- f32 GEMM (indexer path): C = A(M,K) @ B(K,N) ----------------
__launch_bounds__(256)
__global__ void k_gemm(const float* __restrict__ A, const float* __restrict__ B,
                       float* __restrict__ C, int M, int N, int K) {
  __shared__ float As[16][68];
  __shared__ float Bs[16][68];
  int m0 = blockIdx.y * 64, n0 = blockIdx.x * 64;
  int tid = threadIdx.x;
  int ti = tid & 15, tj = tid >> 4;
  int ar = tid >> 2, akq = tid & 3;
  int bkr = tid >> 4, bjq = tid & 15;
  float acc[4][4] = {};
  for (int k0 = 0; k0 < K; k0 += 16) {
    float4 a4 = *(const float4*)&A[(size_t)(m0 + ar) * K + k0 + akq * 4];
    float4 b4 = *(const float4*)&B[(size_t)(k0 + bkr) * N + n0 + bjq * 4];
    As[akq * 4 + 0][ar] = a4.x;
    As[akq * 4 + 1][ar] = a4.y;
    As[akq * 4 + 2][ar] = a4.z;
    As[akq * 4 + 3][ar] = a4.w;
    *(float4*)&Bs[bkr][bjq * 4] = b4;
    __syncthreads();
#pragma unroll
    for (int k = 0; k < 16; ++k) {
      float4 av = *(const float4*)&As[k][ti * 4];
      float4 bv = *(const float4*)&Bs[k][tj * 4];
      float ax[4] = {av.x, av.y, av.z, av.w};
      float bx[4] = {bv.x, bv.y, bv.z, bv.w};
#pragma unroll
      for (int r = 0; r < 4; ++r)
#pragma unroll
        for (int c = 0; c < 4; ++c) acc[r][c] = fmaf(ax[r], bx[c], acc[r][c]);
    }
    __syncthreads();
  }
#pragma unroll
  for (int r = 0; r < 4; ++r) {
    float4 st = make_float4(acc[r][0], acc[r][1], acc[r][2], acc[r][3]);
    *(float4*)&C[(size_t)(m0 + ti * 4 + r) * N + n0 + tj * 4] = st;
  }
}

// ---------------- rope kernels ----------------
__global__ void k_rope_q(float* __restrict__ q, const float* __restrict__ cosT,
                         const float* __restrict__ sinT) {
  int idx = blockIdx.x * 256 + threadIdx.x;
  if (idx >= T_ * H_ * 32) return;
  int i = idx & 31;
  int th = idx >> 5;
  int h = th & 15, t = th >> 4;
  float c = cosT[t * 32 + i], s = sinT[t * 32 + i];
  float* p = q + (size_t)t * 3072 + h * 192 + 128 + 2 * i;
  float e = p[0], o = p[1];
  p[0] = e * c - o * s;
  p[1] = o * c + e * s;
}

__global__ void k_rope_qidx(float* __restrict__ qi, const float* __restrict__ cosT,
                            const float* __restrict__ sinT) {
  int idx = blockIdx.x * 256 + threadIdx.x;
  if (idx >= T_ * IH_ * 32) return;
  int i = idx & 31;
  int th = idx >> 5;
  int h = th & 31, t = th >> 5;
  float c = cosT[t * 32 + i], s = sinT[t * 32 + i];
  float* p = qi + (size_t)t * 4096 + h * 128;
  float a = p[i], b = p[i + 32];
  p[i] = a * c - b * s;
  p[i + 32] = b * c + a * s;
}

__global__ void k_rope_kpe(const float* __restrict__ kpe, const float* __restrict__ cosT,
                           const float* __restrict__ sinT, float* __restrict__ kper) {
  int idx = blockIdx.x * 256 + threadIdx.x;
  if (idx >= T_ * 32) return;
  int i = idx & 31, t = idx >> 5;
  float c = cosT[idx], s = sinT[idx];
  float e = kpe[(size_t)t * 64 + 2 * i], o = kpe[(size_t)t * 64 + 2 * i + 1];
  kper[(size_t)t * 64 + 2 * i] = e * c - o * s;
  kper[(size_t)t * 64 + 2 * i + 1] = o * c + e * s;
}

// ---------------- k_idx ----------------
__launch_bounds__(256)
__global__ void k_kidx(const float* __restrict__ hidden, const float* __restrict__ Wik,
                       const float* __restrict__ gamma, const float* __restrict__ beta,
                       const float* __restrict__ cosT, const float* __restrict__ sinT,
                       float* __restrict__ kidx) {
  int t = blockIdx.x;
  int c = threadIdx.x & 127;
  int s = threadIdx.x >> 7;
  const float* hr = hidden + (size_t)t * HID_;
  float acc = 0.f;
  int k0 = s * (HID_ / 2), k1 = k0 + (HID_ / 2);
  for (int k = k0; k < k1; ++k) acc = fmaf(hr[k], Wik[(size_t)k * ID_ + c], acc);
  __shared__ float part[2][ID_];
  __shared__ float red[128];
  __shared__ float sm[2];
  __shared__ float yn[ID_];
  part[s][c] = acc;
  __syncthreads();
  float yv = 0.f;
  if (s == 0) { yv = part[0][c] + part[1][c]; red[c] = yv; }
  __syncthreads();
  for (int off = 64; off > 0; off >>= 1) {
    if (threadIdx.x < off) red[threadIdx.x] += red[threadIdx.x + off];
    __syncthreads();
  }
  if (threadIdx.x == 0) sm[0] = red[0] * (1.f / ID_);
  __syncthreads();
  float mu = sm[0];
  if (s == 0) { float d = yv - mu; red[c] = d * d; }
  __syncthreads();
  for (int off = 64; off > 0; off >>= 1) {
    if (threadIdx.x < off) red[threadIdx.x] += red[threadIdx.x + off];
    __syncthreads();
  }
  if (threadIdx.x == 0) sm[1] = red[0] * (1.f / ID_);
  __syncthreads();
  if (s == 0) {
    float rstd = rsqrtf(sm[1] + EPS_);
    yn[c] = (yv - mu) * rstd * gamma[c] + beta[c];
  }
  __syncthreads();
  if (threadIdx.x < 32) {
    int i = threadIdx.x;
    float co = cosT[t * 32 + i], si = sinT[t * 32 + i];
    float a = yn[i], b = yn[i + 32];
    kidx[(size_t)t * ID_ + i] = a * co - b * si;
    kidx[(size_t)t * ID_ + i + 32] = b * co + a * si;
  } else if (threadIdx.x >= 64 && threadIdx.x < 128) {
    kidx[(size_t)t * ID_ + threadIdx.x] = yn[threadIdx.x];
  }
}

// ---------------- w_idx ----------------
__launch_bounds__(256)
__global__ void k_widx(const float* __restrict__ hidden, const float* __restrict__ Ww,
                       float* __restrict__ widx) {
  int t = blockIdx.x;
  int j = threadIdx.x & 31, s = threadIdx.x >> 5;
  const float* hr = hidden + (size_t)t * HID_;
  float acc = 0.f;
  int k0 = s * 896, k1 = k0 + 896;
  for (int k = k0; k < k1; ++k) acc = fmaf(hr[k], Ww[(size_t)k * 32 + j], acc);
  __shared__ float red[8][33];
  red[s][j] = acc;
  __syncthreads();
  if (threadIdx.x < 32) {
    float v = 0.f;
#pragma unroll
    for (int r = 0; r < 8; ++r) v += red[r][j];
    widx[(size_t)t * 32 + j] = v * WSCALE_;
  }
}

// ---------------- indexer scores (f32) ----------------
__launch_bounds__(256)
__global__ void k_scores(const float* __restrict__ qidx, const float* __restrict__ kidx,
                         const float* __restrict__ widx, float* __restrict__ scores) {
  int jb = blockIdx.x, tb = blockIdx.y;
  int t0 = tb * 32, j0 = jb * 64;
  if (j0 > t0 + 31) return;
  int tid = threadIdx.x;
  __shared__ float KsT[128][68];
  __shared__ float QsT[128][36];
  __shared__ float Wsh[32][33];
  for (int m = 0; m < 32; ++m) {
    int e = m * 256 + tid;
    int j = e >> 7, d = e & 127;
    KsT[d][j] = kidx[(size_t)(j0 + j) * 128 + d];
  }
  for (int m = 0; m < 4; ++m) {
    int e = m * 256 + tid;
    int i = e >> 5, hh = e & 31;
    Wsh[i][hh] = widx[(size_t)(t0 + i) * 32 + hh];
  }
  int ti = tid & 15, tj = tid >> 4;
  float sacc[2][4] = {};
  for (int h = 0; h < 32; ++h) {
    __syncthreads();
    for (int m = 0; m < 16; ++m) {
      int e = m * 256 + tid;
      int i = e >> 7, d = e & 127;
      QsT[d][i] = qidx[(size_t)(t0 + i) * 4096 + h * 128 + d];
    }
    __syncthreads();
    float lacc[2][4] = {};
    for (int d = 0; d < 128; ++d) {
      float2 a = *(const float2*)&QsT[d][ti * 2];
      float4 b = *(const float4*)&KsT[d][tj * 4];
      lacc[0][0] = fmaf(a.x, b.x, lacc[0][0]);
      lacc[0][1] = fmaf(a.x, b.y, lacc[0][1]);
      lacc[0][2] = fmaf(a.x, b.z, lacc[0][2]);
      lacc[0][3] = fmaf(a.x, b.w, lacc[0][3]);
      lacc[1][0] = fmaf(a.y, b.x, lacc[1][0]);
      lacc[1][1] = fmaf(a.y, b.y, lacc[1][1]);
      lacc[1][2] = fmaf(a.y, b.z, lacc[1][2]);
      lacc[1][3] = fmaf(a.y, b.w, lacc[1][3]);
    }
#pragma unroll
    for (int r = 0; r < 2; ++r) {
      float wv = Wsh[ti * 2 + r][h];
#pragma unroll
      for (int c = 0; c < 4; ++c)
        sacc[r][c] = fmaf(wv, fmaxf(lacc[r][c] * ISCALE_, 0.f), sacc[r][c]);
    }
  }
#pragma unroll
  for (int r = 0; r < 2; ++r) {
    float4 st = make_float4(sacc[r][0], sacc[r][1], sacc[r][2], sacc[r][3]);
    *(float4*)&scores[(size_t)(t0 + ti * 2 + r) * T_ + j0 + tj * 4] = st;
  }
}

// ---------------- top-k threshold ----------------
__launch_bounds__(256)
__global__ void k_topk(const float* __restrict__ scores, unsigned int* __restrict__ kth) {
  int t = blockIdx.x;
  int n = t + 1;
  if (n <= TOPK_) {
    if (threadIdx.x == 0) kth[t] = 0u;
    return;
  }
  unsigned int keys[8];
#pragma unroll
  for (int m = 0; m < 8; ++m) {
    int j = threadIdx.x + m * 256;
    keys[m] = (j < n) ? mono(scores[(size_t)t * T_ + j]) : 0u;
  }
  __shared__ int wred[4];
  unsigned int thr = 0u;
  for (int b = 31; b >= 0; --b) {
    unsigned int cand = thr | (1u << b);
    int c = 0;
#pragma unroll
    for (int m = 0; m < 8; ++m) c += (keys[m] >= cand) ? 1 : 0;
    for (int o = 32; o > 0; o >>= 1) c += __shfl_down(c, o, 64);
    if ((threadIdx.x & 63) == 0) wred[threadIdx.x >> 6] = c;
    __syncthreads();
    int total = wred[0] + wred[1] + wred[2] + wred[3];
    if (total >= TOPK_) thr = cand;
    __syncthreads();
  }
  if (threadIdx.x == 0) kth[t] = thr;
}

// ---------------- casts for flash: Qb/Kb (head-major bf16) ----------------
__launch_bounds__(256)
__global__ void k_cast_flash(const float* __restrict__ qbuf, const float* __restrict__ kvb,
                             const float* __restrict__ kper,
                             unsigned short* __restrict__ Qb, unsigned short* __restrict__ Kb) {
  int t = blockIdx.x;
  int tid = threadIdx.x;
#pragma unroll
  for (int i = 0; i < 12; ++i) {
    int e = i * 256 + tid;  // 0..3071
    int h = e / 192, d = e % 192;
    Qb[((size_t)h * T_ + t) * 192 + d] = f2bf(qbuf[(size_t)t * 3072 + e]);
    float kv = (d < 128) ? kvb[(size_t)t * 4096 + h * 256 + d]
                         : kper[(size_t)t * 64 + (d - 128)];
    Kb[((size_t)h * T_ + t) * 192 + d] = f2bf(kv);
  }
}

// ---------------- cast V transposed: Vt[h][d][t] bf16 ----------------
__launch_bounds__(256)
__global__ void k_cast_v(const float* __restrict__ kvb, unsigned short* __restrict__ Vt) {
  __shared__ unsigned short vt[128][137];
  int h = blockIdx.y, t0 = blockIdx.x * 128;
  int tid = threadIdx.x;
#pragma unroll
  for (int i = 0; i < 64; ++i) {
    int e = i * 256 + tid;
    int tl = e >> 7, d = e & 127;
    vt[tl][d] = f2bf(kvb[(size_t)(t0 + tl) * 4096 + h * 256 + 128 + d]);
  }
  __syncthreads();
#pragma unroll
  for (int i = 0; i < 64; ++i) {
    int e = i * 256 + tid;
    int d = e >> 7, tl = e & 127;
    Vt[((size_t)h * 128 + d) * T_ + t0 + tl] = vt[tl][d];
  }
}

// ---------------- MFMA flash attention with top-k mask ----------------
// block: 32 q-rows x 1 head; j-tile 32; bf16 MFMA QK^T and PV, f32 softmax.
__launch_bounds__(256)
__global__ void k_flash2(const unsigned short* __restrict__ Qb,
                         const unsigned short* __restrict__ Kb,
                         const unsigned short* __restrict__ Vt,
                         const float* __restrict__ scores,
                         const unsigned int* __restrict__ kth,
                         unsigned short* __restrict__ obf) {
  __shared__ unsigned short Qs[32][200];
  __shared__ unsigned short Ks[32][200];
  __shared__ unsigned short VsT[128][40];
  __shared__ float Ss[32][33];
  __shared__ unsigned short Ps[32][40];
  __shared__ float m_s[32], l_s[32], al_s[32];

  int t0 = blockIdx.x * 32, h = blockIdx.y;
  int tid = threadIdx.x;
  int w = tid >> 6, lane = tid & 63;
  int quad = lane >> 4, l16 = lane & 15;
  int wr = w & 1, wc = w >> 1;  // QK quadrant; PV: rows 16*wr, col blocks 4*wc..

  // stage Q once (32 x 192 bf16)
#pragma unroll
  for (int i = 0; i < 3; ++i) {
    int c = i * 256 + tid;  // 0..767
    int row = c / 24, off = (c % 24) * 8;
    *(uint4*)&Qs[row][off] =
        *(const uint4*)&Qb[((size_t)h * T_ + t0 + row) * 192 + off];
  }
  if (tid < 32) { m_s[tid] = -INFINITY; l_s[tid] = 0.f; }

  f32x4 Of[4] = {};

  int srow = tid >> 3;        // softmax row 0..31
  int c8 = tid & 7;           // softmax col group
  int ig = t0 + srow;

  int njt = blockIdx.x + 1;
  for (int jt = 0; jt < njt; ++jt) {
    int j0 = jt * 32;
    __syncthreads();
    // stage K (32 x 192) and V^T (128 x 32)
#pragma unroll
    for (int i = 0; i < 3; ++i) {
      int c = i * 256 + tid;
      int row = c / 24, off = (c % 24) * 8;
      *(uint4*)&Ks[row][off] =
          *(const uint4*)&Kb[((size_t)h * T_ + j0 + row) * 192 + off];
    }
#pragma unroll
    for (int i = 0; i < 2; ++i) {
      int c = i * 256 + tid;  // 0..511
      int d = c >> 2, off = (c & 3) * 8;
      *(uint4*)&VsT[d][off] =
          *(const uint4*)&Vt[((size_t)h * 128 + d) * T_ + j0 + off];
    }
    __syncthreads();

    // QK^T quadrant (wr, wc): S[16wr.., 16wc..]
    f32x4 Sacc = {};
#pragma unroll
    for (int kk = 0; kk < 6; ++kk) {
      bf16x8 a = *(const bf16x8*)&Qs[16 * wr + l16][kk * 32 + quad * 8];
      bf16x8 b = *(const bf16x8*)&Ks[16 * wc + l16][kk * 32 + quad * 8];
      Sacc = __builtin_amdgcn_mfma_f32_16x16x32_bf16(a, b, Sacc, 0, 0, 0);
    }
#pragma unroll
    for (int r = 0; r < 4; ++r)
      Ss[16 * wr + quad * 4 + r][16 * wc + l16] = Sacc[r];
    __syncthreads();

    // masked online softmax (8 threads per row, 4 cols each)
    float mold = m_s[srow];
    unsigned int kt = kth[ig];
    float4 s4 = *(const float4*)(scores + (size_t)ig * T_ + j0 + 4 * c8);
    float sv[4] = {s4.x, s4.y, s4.z, s4.w};
    float v[4];
#pragma unroll
    for (int c = 0; c < 4; ++c) {
      int jg = j0 + 4 * c8 + c;
      float sc = Ss[srow][4 * c8 + c];
      bool ok = (jg <= ig) && (mono(sv[c]) >= kt);
      v[c] = ok ? sc * SCALE_ : -INFINITY;
    }
    float tmax = fmaxf(fmaxf(v[0], v[1]), fmaxf(v[2], v[3]));
#pragma unroll
    for (int o = 1; o < 8; o <<= 1) tmax = fmaxf(tmax, __shfl_xor(tmax, o, 8));
    float mn = fmaxf(mold, tmax);
    float alpha = (mold == -INFINITY) ? 0.f : expf(mold - mn);
    float p[4], psum = 0.f;
#pragma unroll
    for (int c = 0; c < 4; ++c) {
      p[c] = (v[c] == -INFINITY) ? 0.f : expf(v[c] - mn);
      psum += p[c];
    }
#pragma unroll
    for (int o = 1; o < 8; o <<= 1) psum += __shfl_xor(psum, o, 8);
    if (c8 == 0) {
      m_s[srow] = mn;
      al_s[srow] = alpha;
      l_s[srow] = alpha * l_s[srow] + psum;
    }
#pragma unroll
    for (int c = 0; c < 4; ++c) Ps[srow][4 * c8 + c] = f2bf(p[c]);
    __syncthreads();

    // PV: O[16*wr.., 16*(4*wc+i)..] += P * V
    float arow[4];
#pragma unroll
    for (int r = 0; r < 4; ++r) arow[r] = al_s[16 * wr + quad * 4 + r];
    bf16x8 pa = *(const bf16x8*)&Ps[16 * wr + l16][quad * 8];
#pragma unroll
    for (int i = 0; i < 4; ++i) {
#pragma unroll
      for (int r = 0; r < 4; ++r) Of[i][r] *= arow[r];
      bf16x8 vb = *(const bf16x8*)&VsT[16 * (4 * wc + i) + l16][quad * 8];
      Of[i] = __builtin_amdgcn_mfma_f32_16x16x32_bf16(pa, vb, Of[i], 0, 0, 0);
    }
  }

  // epilogue: normalize and write bf16 O (t, h*128+col)
  float linv[4];
#pragma unroll
  for (int r = 0; r < 4; ++r) linv[r] = 1.f / l_s[16 * wr + quad * 4 + r];
#pragma unroll
  for (int i = 0; i < 4; ++i) {
#pragma unroll
    for (int r = 0; r < 4; ++r) {
      int row = t0 + 16 * wr + quad * 4 + r;
      int col = 16 * (4 * wc + i) + l16;
      obf[(size_t)row * 2048 + h * 128 + col] = f2bf(Of[i][r] * linv[r]);
    }
  }
}

}  // namespace

extern "C" void kernel_launch(void* const* d_in, const int* in_sizes, int n_in,
                              void* d_out, int out_size, void* d_ws, size_t ws_size,
                              hipStream_t stream) {
  (void)in_sizes; (void)n_in; (void)out_size; (void)ws_size;
  const int*   positions = (const int*)d_in[0];
  const float* hidden  = (const float*)d_in[1];
  const float* q_c     = (const float*)d_in[2];
  const float* kv_c    = (const float*)d_in[3];
  const float* k_pe    = (const float*)d_in[4];
  const float* q_ln    = (const float*)d_in[5];
  const float* kv_ln   = (const float*)d_in[6];
  const float* Wq_b    = (const float*)d_in[7];
  const float* Wkv_b   = (const float*)d_in[8];
  const float* Wo      = (const float*)d_in[9];
  const float* Wiq     = (const float*)d_in[10];
  const float* Wik     = (const float*)d_in[11];
  const float* ik_g    = (const float*)d_in[12];
  const float* ik_b    = (const float*)d_in[13];
  const float* Ww      = (const float*)d_in[14];
  float* out = (float*)d_out;

  float* ws = (float*)d_ws;
  size_t off = 0;
  float* cosT = ws + off; off += (size_t)T_ * 32;
  float* sinT = ws + off; off += (size_t)T_ * 32;
  float* qcn  = ws + off; off += (size_t)T_ * QLR_;
  float* kvn  = ws + off; off += (size_t)T_ * KVLR_;
  float* qbuf = ws + off; off += (size_t)T_ * H_ * 192;
  float* kvb  = ws + off; off += (size_t)T_ * H_ * 256;
  float* qidx = ws + off; off += (size_t)T_ * 4096;   // overlaid by Qb/Kb/obf later
  float* kidx = ws + off; off += (size_t)T_ * ID_;
  float* widx = ws + off; off += (size_t)T_ * IH_;
  float* kper = ws + off; off += (size_t)T_ * 64;
  float* scores = ws + off; off += (size_t)T_ * T_;   // early hosts Wqt+Wkvt
  unsigned int* kth = (unsigned int*)(ws + off); off += T_;
  unsigned short* qcn_bf = (unsigned short*)(ws + off); off += (size_t)T_ * QLR_ / 2;
  unsigned short* kvn_bf = (unsigned short*)(ws + off); off += (size_t)T_ * KVLR_ / 2;
  unsigned short* Wot = (unsigned short*)(ws + off); off += (size_t)HID_ * 2048 / 2;
  unsigned short* Vt  = (unsigned short*)(ws + off); off += (size_t)H_ * 128 * T_ / 2;

  // overlays
  unsigned short* Wqt  = (unsigned short*)scores;                  // 3072x1536 bf16
  unsigned short* Wkvt = Wqt + (size_t)3072 * 1536;                // 4096x512 bf16
  unsigned short* Qb   = (unsigned short*)qidx;                    // (16,2048,192)
  unsigned short* Kb   = Qb + (size_t)H_ * T_ * 192;               // (16,2048,192)
  unsigned short* obf  = Kb + (size_t)H_ * T_ * 192;               // (2048,2048)

  k_tables<<<dim3(T_ * 32 / 256), dim3(256), 0, stream>>>(positions, cosT, sinT);
  k_rms<QLR_><<<dim3(T_), dim3(256), 0, stream>>>(q_c, q_ln, qcn, qcn_bf);
  k_rms<KVLR_><<<dim3(T_), dim3(256), 0, stream>>>(kv_c, kv_ln, kvn, kvn_bf);
  k_tc<<<dim3(3072 / 64, QLR_ / 64), dim3(256), 0, stream>>>(Wq_b, Wqt, QLR_, 3072);
  k_tc<<<dim3(4096 / 64, KVLR_ / 64), dim3(256), 0, stream>>>(Wkv_b, Wkvt, KVLR_, 4096);
  k_tc<<<dim3(HID_ / 64, 2048 / 64), dim3(256), 0, stream>>>(Wo, Wot, 2048, HID_);
  k_gemm_bf<<<dim3(3072 / 128, T_ / 128), dim3(256), 0, stream>>>(qcn_bf, Wqt, qbuf, T_, 3072, QLR_);
  k_rope_q<<<dim3(T_ * H_ * 32 / 256), dim3(256), 0, stream>>>(qbuf, cosT, sinT);
  k_gemm_bf<<<dim3(4096 / 128, T_ / 128), dim3(256), 0, stream>>>(kvn_bf, Wkvt, kvb, T_, 4096, KVLR_);
  k_gemm<<<dim3(4096 / 64, T_ / 64), dim3(256), 0, stream>>>(qcn, Wiq, qidx, T_, 4096, QLR_);
  k_rope_qidx<<<dim3(T_ * IH_ * 32 / 256), dim3(256), 0, stream>>>(qidx, cosT, sinT);
  k_kidx<<<dim3(T_), dim3(256), 0, stream>>>(hidden, Wik, ik_g, ik_b, cosT, sinT, kidx);
  k_widx<<<dim3(T_), dim3(256), 0, stream>>>(hidden, Ww, widx);
  k_rope_kpe<<<dim3(T_ * 32 / 256), dim3(256), 0, stream>>>(k_pe, cosT, sinT, kper);
  k_scores<<<dim3(T_ / 64, T_ / 32), dim3(256), 0, stream>>>(qidx, kidx, widx, scores);
  k_topk<<<dim3(T_), dim3(256), 0, stream>>>(scores, kth);
  // casts AFTER k_scores (Qb/Kb/obf overlay qidx)
  k_cast_flash<<<dim3(T_), dim3(256), 0, stream>>>(qbuf, kvb, kper, Qb, Kb);
  k_cast_v<<<dim3(T_ / 128, H_), dim3(256), 0, stream>>>(kvb, Vt);
  k_flash2<<<dim3(T_ / 32, H_), dim3(256), 0, stream>>>(Qb, Kb, Vt, scores, kth, obf);
  k_gemm_bf<<<dim3(HID_ / 128, T_ / 128), dim3(256), 0, stream>>>(obf, Wot, out, T_, HID_, 2048);
}